// Round 1
// baseline (431.365 us; speedup 1.0000x reference)
//
#include <hip/hip_runtime.h>
#include <hip/hip_bf16.h>

// Problem constants (from reference): B=8192, T=512, IN=1, H=20, OUT=1
#define B_TOTAL 8192
#define T_LEN   512
#define H       20
#define NB      16                // batches per block
#define THREADS (NB * H)          // 320 = 5 waves
#define HP      24                // padded hidden stride (floats) for LDS

__device__ __forceinline__ float fast_tanh(float x) {
    // tanh(x) = 1 - 2/(e^{2x}+1); saturates correctly for |x| large.
    float e = __expf(2.0f * x);
    return 1.0f - 2.0f * __builtin_amdgcn_rcpf(e + 1.0f);
}

// acc += dot(h[0..19], w[0..19]); h read from LDS via float4 (ds_read_b128)
__device__ __forceinline__ float dot20acc(const float* hp, const float* w, float acc) {
    float hv[H];
#pragma unroll
    for (int q = 0; q < 5; ++q)
        ((float4*)hv)[q] = ((const float4*)hp)[q];
#pragma unroll
    for (int k = 0; k < H; ++k)
        acc = fmaf(hv[k], w[k], acc);
    return acc;
}

__global__ __launch_bounds__(THREADS) void rnn_fused(
    const float* __restrict__ x,     // [B, T] (IN = 1)
    const float* __restrict__ w_ih0, // [H, 1]
    const float* __restrict__ w_hh0, // [H, H]
    const float* __restrict__ b_ih0,
    const float* __restrict__ b_hh0,
    const float* __restrict__ w_ih1, // [H, H]
    const float* __restrict__ w_hh1,
    const float* __restrict__ b_ih1,
    const float* __restrict__ b_hh1,
    const float* __restrict__ w_ih2,
    const float* __restrict__ w_hh2,
    const float* __restrict__ b_ih2,
    const float* __restrict__ b_hh2,
    const float* __restrict__ fc_w,  // [1, H]
    const float* __restrict__ fc_b,  // [1]
    float* __restrict__ out)         // [B]
{
    __shared__ float xs[NB][T_LEN];
    __shared__ float h0[2][NB][HP];
    __shared__ float h1[2][NB][HP];
    __shared__ float h2[2][NB][HP];

    const int tid = threadIdx.x;
    const int b   = tid / H;              // 0..NB-1
    const int j   = tid % H;              // 0..H-1
    const int gb  = blockIdx.x * NB + b;  // global batch row

    // Stage this block's x rows into LDS (coalesced).
    for (int i = tid; i < NB * T_LEN; i += THREADS) {
        int bb = i >> 9;          // / T_LEN
        int tt = i & (T_LEN - 1); // % T_LEN
        xs[bb][tt] = x[((size_t)(blockIdx.x * NB + bb) << 9) + tt];
    }

    // Per-thread weight rows (row j of each matrix) into registers.
    float whh0r[H], wih1r[H], whh1r[H], wih2r[H], whh2r[H];
#pragma unroll
    for (int k = 0; k < H; ++k) {
        whh0r[k] = w_hh0[j * H + k];
        wih1r[k] = w_ih1[j * H + k];
        whh1r[k] = w_hh1[j * H + k];
        wih2r[k] = w_ih2[j * H + k];
        whh2r[k] = w_hh2[j * H + k];
    }
    const float wih0j = w_ih0[j];
    const float bias0 = b_ih0[j] + b_hh0[j];
    const float bias1 = b_ih1[j] + b_hh1[j];
    const float bias2 = b_ih2[j] + b_hh2[j];

    // h(t=-1) = 0 lives in buffer 1 (prv of t=0).
    h0[1][b][j] = 0.0f;
    h1[1][b][j] = 0.0f;
    h2[1][b][j] = 0.0f;
    __syncthreads();

    int cur = 0;
    for (int t = 0; t < T_LEN; ++t) {
        const int prv = cur ^ 1;

        // ---- layer 0: h0n = tanh(x_t * w_ih0[j] + bias0 + h0_prev . whh0_row_j)
        float acc0 = fmaf(xs[b][t], wih0j, bias0);
        acc0 = dot20acc(&h0[prv][b][0], whh0r, acc0);
        float h0n = fast_tanh(acc0);
        h0[cur][b][j] = h0n;
        __syncthreads();

        // ---- layer 1: h1n = tanh(h0_new . wih1_row_j + bias1 + h1_prev . whh1_row_j)
        float acc1 = bias1;
        acc1 = dot20acc(&h0[cur][b][0], wih1r, acc1);
        acc1 = dot20acc(&h1[prv][b][0], whh1r, acc1);
        float h1n = fast_tanh(acc1);
        h1[cur][b][j] = h1n;
        __syncthreads();

        // ---- layer 2
        float acc2 = bias2;
        acc2 = dot20acc(&h1[cur][b][0], wih2r, acc2);
        acc2 = dot20acc(&h2[prv][b][0], whh2r, acc2);
        float h2n = fast_tanh(acc2);
        h2[cur][b][j] = h2n;
        __syncthreads();

        cur ^= 1;
    }

    // Final: out[b] = fc_w . h2_last + fc_b   (last written buffer is 1: t=511 -> cur=1)
    if (j == 0) {
        float acc = fc_b[0];
        const float* hp = &h2[1][b][0];
#pragma unroll
        for (int k = 0; k < H; ++k)
            acc = fmaf(hp[k], fc_w[k], acc);
        out[gb] = acc;
    }
}

extern "C" void kernel_launch(void* const* d_in, const int* in_sizes, int n_in,
                              void* d_out, int out_size, void* d_ws, size_t ws_size,
                              hipStream_t stream) {
    const float* x     = (const float*)d_in[0];
    const float* w_ih0 = (const float*)d_in[1];
    const float* w_hh0 = (const float*)d_in[2];
    const float* b_ih0 = (const float*)d_in[3];
    const float* b_hh0 = (const float*)d_in[4];
    const float* w_ih1 = (const float*)d_in[5];
    const float* w_hh1 = (const float*)d_in[6];
    const float* b_ih1 = (const float*)d_in[7];
    const float* b_hh1 = (const float*)d_in[8];
    const float* w_ih2 = (const float*)d_in[9];
    const float* w_hh2 = (const float*)d_in[10];
    const float* b_ih2 = (const float*)d_in[11];
    const float* b_hh2 = (const float*)d_in[12];
    const float* fc_w  = (const float*)d_in[13];
    const float* fc_b  = (const float*)d_in[14];
    float* out = (float*)d_out;

    rnn_fused<<<B_TOTAL / NB, THREADS, 0, stream>>>(
        x, w_ih0, w_hh0, b_ih0, b_hh0,
        w_ih1, w_hh1, b_ih1, b_hh1,
        w_ih2, w_hh2, b_ih2, b_hh2,
        fc_w, fc_b, out);
}